// Round 1
// baseline (429.705 us; speedup 1.0000x reference)
//
#include <hip/hip_runtime.h>
#include <math.h>

#define TN 2048            // T
#define LOGT 11
#define NF 4096            // Bluestein FFT length
#define LOGNF 12
#define NB 64              // batch
#define LF 6142LL          // L = 3T-2
#define L2F 12284LL        // 2L
#define PI_D 3.14159265358979323846264338327950288

typedef double2 cpx;

__device__ __forceinline__ cpx cmk(double a, double b){ cpx r; r.x=a; r.y=b; return r; }
__device__ __forceinline__ cpx cadd(cpx a, cpx b){ return cmk(a.x+b.x, a.y+b.y); }
__device__ __forceinline__ cpx csub(cpx a, cpx b){ return cmk(a.x-b.x, a.y-b.y); }
__device__ __forceinline__ cpx cmul(cpx a, cpx b){ return cmk(a.x*b.x - a.y*b.y, a.x*b.y + a.y*b.x); }
// a * conj(b)
__device__ __forceinline__ cpx cmulc(cpx a, cpx b){ return cmk(a.x*b.x + a.y*b.y, a.y*b.x - a.x*b.y); }

// ---------- FFT: DIF forward (natural in -> bit-rev out), DIT inverse (bit-rev in
// -> natural out, no 1/N scaling). tw = tw4096 table: tw[k] = e^{-2pi i k/4096}, k<2048.
// Twiddle for half-size m: e^{-2pi i pos/(2m)} = tw[pos << (11 - log2(m))].
template<int LOGN>
__device__ void fft_dif(cpx* buf, const cpx* tw){
  const int N = 1 << LOGN;
  for (int lm = LOGN - 1; lm >= 0; lm--){
    int m = 1 << lm;
    __syncthreads();
    for (int i = threadIdx.x; i < (N >> 1); i += 256){
      int pos = i & (m - 1);
      int i1 = ((i >> lm) << (lm + 1)) | pos;
      int i2 = i1 + m;
      cpx a = buf[i1], b = buf[i2];
      cpx w = tw[pos << (11 - lm)];
      buf[i1] = cadd(a, b);
      buf[i2] = cmul(csub(a, b), w);
    }
  }
  __syncthreads();
}

template<int LOGN>
__device__ void fft_dit_inv(cpx* buf, const cpx* tw){
  const int N = 1 << LOGN;
  for (int lm = 0; lm <= LOGN - 1; lm++){
    int m = 1 << lm;
    __syncthreads();
    for (int i = threadIdx.x; i < (N >> 1); i += 256){
      int pos = i & (m - 1);
      int i1 = ((i >> lm) << (lm + 1)) | pos;
      int i2 = i1 + m;
      cpx a = buf[i1];
      cpx w = tw[pos << (11 - lm)];
      cpx b = cmulc(buf[i2], w);
      buf[i1] = cadd(a, b);
      buf[i2] = csub(a, b);
    }
  }
  __syncthreads();
}

// ---------- K1: filter time series. arr[fid][m], fid: 0=f,1=g,2=fp,3=gp (f,fp reversed)
__global__ __launch_bounds__(256) void k_arr(
    const float* fw1, const float* fb1, const float* fw2, const float* fb2,
    const float* gw1, const float* gb1, const float* gw2, const float* gb2,
    const float* pw1, const float* pb1, const float* pw2, const float* pb2,
    const float* qw1, const float* qb1, const float* qw2, const float* qb2,
    double* arr)
{
  int gid = blockIdx.x * 256 + threadIdx.x;
  int fid = gid >> LOGT;
  int m = gid & (TN - 1);
  const float *W1, *B1, *W2, *B2;
  if (fid == 0){ W1=fw1; B1=fb1; W2=fw2; B2=fb2; }
  else if (fid == 1){ W1=gw1; B1=gb1; W2=gw2; B2=gb2; }
  else if (fid == 2){ W1=pw1; B1=pb1; W2=pw2; B2=pb2; }
  else { W1=qw1; B1=qb1; W2=qw2; B2=qb2; }
  int s = (fid == 0 || fid == 2) ? (TN - 1 - m) : m;
  double sv = (double)s;
  double z = (double)B2[0];
  #pragma unroll
  for (int h = 0; h < 5; h++)
    z += (double)W2[h] * tanh(sv * (double)W1[h] + (double)B1[h]);
  arr[fid * TN + m] = z * exp(-5.0 * sv);
}

// ---------- K2: tables. tw4096, Q[j] = beta(j)*chirp(j), g2[r] = gamma(r)^2 (with 1/L^2)
__global__ __launch_bounds__(256) void k_tables(cpx* tw, cpx* Q, cpx* g2){
  long long i = blockIdx.x * 256 + threadIdx.x;   // 0..2047
  double s, c;
  sincos(-2.0 * PI_D * (double)i / 4096.0, &s, &c);
  tw[i] = cmk(c, s);
  // Q[j] = e^{2pi i ((2T-2) j mod L)/L} * e^{i pi (j^2 mod 2L)/L}
  long long a = ((2LL * TN - 2) * i) % LF;
  long long b = (i * i) % L2F;
  long long comb = (2 * a + b) % L2F;
  sincos(PI_D * (double)comb / (double)LF, &s, &c);
  Q[i] = cmk(c, s);
  // gamma(r) = (1/L) e^{2pi i ((2T-2+r)(T-1) mod L)/L} e^{i pi (r^2 mod 2L)/L}; store gamma^2
  long long a2 = ((2LL * TN - 2 + i) * (TN - 1)) % LF;
  long long b2 = (i * i) % L2F;
  long long comb2 = (2 * a2 + b2) % L2F;
  double phi = PI_D * (double)comb2 / (double)LF;
  double invL2 = 1.0 / ((double)LF * (double)LF);
  sincos(2.0 * phi, &s, &c);
  g2[i] = cmk(c * invL2, s * invL2);
}

// ---------- K3: H spectra. Hs[f][j] = sum_m arr[f][m] e^{-2pi i (m+T-1)(j+T-1)/L}
__global__ __launch_bounds__(256) void k_hs(const double* arr, cpx* Hs){
  int f = blockIdx.x >> 6;
  int jbase = (blockIdx.x & 63) * 32;
  int chunk = threadIdx.x & 7;     // 8 m-chunks of 256
  int jl = threadIdx.x >> 3;       // 32 j per block
  long long j = jbase + jl;
  long long jj = j + TN - 1;       // < L
  double s, c;
  sincos(-2.0 * PI_D * (double)jj / (double)LF, &s, &c);
  cpx W = cmk(c, s);
  long long m0 = (long long)chunk * 256;
  long long p0 = ((m0 + TN - 1) * jj) % LF;
  sincos(-2.0 * PI_D * (double)p0 / (double)LF, &s, &c);
  cpx ph = cmk(c, s);
  const double* a = arr + f * TN;
  cpx acc = cmk(0.0, 0.0);
  for (int m = (int)m0; m < (int)m0 + 256; m++){
    double av = a[m];
    acc.x += av * ph.x;
    acc.y += av * ph.y;
    ph = cmul(ph, W);
  }
  __shared__ cpx part[256];
  part[threadIdx.x] = acc;
  __syncthreads();
  if (chunk == 0){
    cpx tot = cmk(0.0, 0.0);
    for (int q = 0; q < 8; q++) tot = cadd(tot, part[(jl << 3) + q]);
    Hs[f * TN + j] = tot;
  }
}

// ---------- K4: chirp FFT (bit-reversed order, matching DIF output order)
__global__ __launch_bounds__(256) void k_chat(const cpx* tw, cpx* chat){
  __shared__ cpx buf[NF];
  for (int m = threadIdx.x; m < NF; m += 256){
    long long mm = (m <= 2048) ? m : (NF - m);
    long long q = (mm * mm) % L2F;
    double s, c;
    sincos(-PI_D * (double)q / (double)LF, &s, &c);
    buf[m] = cmk(c, s);
  }
  fft_dif<LOGNF>(buf, tw);
  for (int i = threadIdx.x; i < NF; i += 256) chat[i] = buf[i];
}

// ---------- SO(3) helpers
__device__ __forceinline__ void mat_mul3(double* D, const double* A, const double* B){
  double r[9];
  #pragma unroll
  for (int i = 0; i < 3; i++)
    #pragma unroll
    for (int j = 0; j < 3; j++)
      r[i*3+j] = A[i*3]*B[j] + A[i*3+1]*B[3+j] + A[i*3+2]*B[6+j];
  #pragma unroll
  for (int k = 0; k < 9; k++) D[k] = r[k];
}

__device__ __forceinline__ void rod3(double* M, const double* a1, const double* a2,
                                     double z1, double z2){
  double G[9];
  #pragma unroll
  for (int k = 0; k < 9; k++) G[k] = a1[k]*z1 + a2[k]*z2;
  double wx = G[7], wy = G[2], wz = G[3];
  double th2 = wx*wx + wy*wy + wz*wz;
  double sa, cb;
  if (th2 < 1e-12){ sa = 1.0 - th2/6.0; cb = 0.5 - th2/24.0; }
  else { double th = sqrt(th2); sa = sin(th)/th; cb = (1.0 - cos(th))/th2; }
  double w[3] = {wx, wy, wz};
  #pragma unroll
  for (int i = 0; i < 3; i++)
    #pragma unroll
    for (int j = 0; j < 3; j++){
      double v = sa * G[i*3+j] + cb * (w[i]*w[j]);
      if (i == j) v += 1.0 - cb * th2;
      M[i*3+j] = v;
    }
}

// ---------- K5: per-batch inclusive scan of rotations. Ascan[b][t][9] = M1*...*Mt
__global__ __launch_bounds__(256) void k_scan(const float* x, const float* A1f,
                                              const float* A2f, double* Ascan){
  int b = blockIdx.x;
  int k = threadIdx.x;
  __shared__ double S[256][9];
  double a1[9], a2[9];
  #pragma unroll
  for (int i = 0; i < 3; i++)
    #pragma unroll
    for (int j = 0; j < 3; j++){
      a1[i*3+j] = (double)A1f[i*3+j] - (double)A1f[j*3+i];
      a2[i*3+j] = (double)A2f[i*3+j] - (double)A2f[j*3+i];
    }
  const float* xb = x + (size_t)b * TN * 2;
  // pass 1: chunk product (8 steps per thread)
  double C[9] = {1,0,0, 0,1,0, 0,0,1};
  for (int i = 0; i < 8; i++){
    int t = k * 8 + i;
    if (t >= 1){
      double M[9];
      rod3(M, a1, a2, (double)xb[2*t], (double)xb[2*t+1]);
      mat_mul3(C, C, M);
    }
  }
  #pragma unroll
  for (int q = 0; q < 9; q++) S[k][q] = C[q];
  __syncthreads();
  // Hillis-Steele inclusive scan over 256 chunk products (non-commutative, left=earlier)
  for (int ofs = 1; ofs < 256; ofs <<= 1){
    double Lm[9], Rm[9];
    bool act = (k >= ofs);
    if (act){
      #pragma unroll
      for (int q = 0; q < 9; q++){ Lm[q] = S[k-ofs][q]; Rm[q] = S[k][q]; }
    }
    __syncthreads();
    if (act){
      double P[9];
      mat_mul3(P, Lm, Rm);
      #pragma unroll
      for (int q = 0; q < 9; q++) S[k][q] = P[q];
    }
    __syncthreads();
  }
  // pass 2: exclusive prefix * local running product
  double P[9];
  if (k == 0){
    P[0]=1; P[1]=0; P[2]=0; P[3]=0; P[4]=1; P[5]=0; P[6]=0; P[7]=0; P[8]=1;
  } else {
    #pragma unroll
    for (int q = 0; q < 9; q++) P[q] = S[k-1][q];
  }
  for (int i = 0; i < 8; i++){
    int t = k * 8 + i;
    if (t >= 1){
      double M[9];
      rod3(M, a1, a2, (double)xb[2*t], (double)xb[2*t+1]);
      mat_mul3(P, P, M);
    }
    double* dst = Ascan + ((size_t)b * TN + t) * 9;
    #pragma unroll
    for (int q = 0; q < 9; q++) dst[q] = P[q];
  }
}

// ---------- K6: 2048-pt FFT of each channel of A -> natural-order spectrum U
__global__ __launch_bounds__(256) void k_fft_u(const double* Ascan, const cpx* tw, cpx* U){
  int bc = blockIdx.x;
  int b = bc / 9, c = bc % 9;
  __shared__ cpx buf[TN];
  for (int t = threadIdx.x; t < TN; t += 256)
    buf[t] = cmk(Ascan[((size_t)b * TN + t) * 9 + c], 0.0);
  fft_dif<LOGT>(buf, tw);
  cpx* dst = U + ((size_t)b * 9 + c) * TN;
  for (int i = threadIdx.x; i < TN; i += 256){
    int r = __brev((unsigned)i) >> (32 - LOGT);
    dst[r] = buf[i];
  }
}

// ---------- K7: main CZT kernel. Per (b,c): 4x (stage -> FFT -> xChat -> IFFT), combine.
__global__ __launch_bounds__(256) void k_main(const cpx* U, const cpx* Hs, const cpx* tw,
                                              const cpx* chat, const cpx* Q, const cpx* g2,
                                              float* out){
  int bc = blockIdx.x;
  int b = bc / 9, c = bc % 9;
  int ct = (c % 3) * 3 + (c / 3);   // transposed channel (inv(A) = A^T for SO(3))
  const cpx* Uc  = U + ((size_t)b * 9 + c) * TN;
  const cpx* Uct = U + ((size_t)b * 9 + ct) * TN;
  __shared__ cpx buf[NF];
  cpx pst[8], acc[8];
  #pragma unroll
  for (int i = 0; i < 8; i++) acc[i] = cmk(0.0, 0.0);
  for (int p = 0; p < 4; p++){            // AA(Uir,Hf), AB(Ur,Hg), BA(Uir,Hfp), BB(Ur,Hgp)
    const cpx* Us = (p & 1) ? Uc : Uct;
    const cpx* H = Hs + p * TN;
    for (int j = threadIdx.x; j < TN; j += 256){
      buf[j] = cmul(cmul(Us[j], H[j]), Q[j]);
      buf[j + TN] = cmk(0.0, 0.0);
    }
    fft_dif<LOGNF>(buf, tw);
    for (int i = threadIdx.x; i < NF; i += 256)
      buf[i] = cmul(buf[i], chat[i]);
    fft_dit_inv<LOGNF>(buf, tw);
    #pragma unroll
    for (int i = 0; i < 8; i++){
      cpx v = buf[threadIdx.x + (i << 8)];
      if ((p & 1) == 0) pst[i] = v;
      else acc[i] = cadd(acc[i], cmul(pst[i], v));
    }
    __syncthreads();   // before next pair overwrites buf
  }
  const double sc = 1.0 / (4096.0 * 4096.0);   // two unscaled inverse FFTs multiplied
  #pragma unroll
  for (int i = 0; i < 8; i++){
    int r = threadIdx.x + (i << 8);
    cpx g = g2[r];
    double re = (acc[i].x * g.x - acc[i].y * g.y) * sc;
    out[((size_t)b * TN + r) * 9 + c] = (float)re;
  }
}

extern "C" void kernel_launch(void* const* d_in, const int* in_sizes, int n_in,
                              void* d_out, int out_size, void* d_ws, size_t ws_size,
                              hipStream_t stream){
  const float* x  = (const float*)d_in[0];
  const float* A1 = (const float*)d_in[1];
  const float* A2 = (const float*)d_in[2];
  const float* fpar[16];
  for (int i = 0; i < 16; i++) fpar[i] = (const float*)d_in[3 + i];
  float* out = (float*)d_out;

  // workspace carve (units: doubles). total = 28,672,000 bytes
  double* ws = (double*)d_ws;
  size_t o = 0;
  double* arr  = ws + o;        o += 4 * TN;                 // 8192
  cpx* Hs      = (cpx*)(ws + o); o += 2 * 4 * TN;            // 4x2048 cpx
  cpx* tw      = (cpx*)(ws + o); o += 2 * TN;                // 2048 cpx
  cpx* chat    = (cpx*)(ws + o); o += 2 * NF;                // 4096 cpx
  cpx* Q       = (cpx*)(ws + o); o += 2 * TN;
  cpx* g2      = (cpx*)(ws + o); o += 2 * TN;
  double* Asc  = ws + o;        o += (size_t)NB * TN * 9;    // 9.4 MB
  cpx* U       = (cpx*)(ws + o); o += 2 * (size_t)NB * 9 * TN; // 18.9 MB

  k_arr<<<32, 256, 0, stream>>>(fpar[0], fpar[1], fpar[2], fpar[3],
                                fpar[4], fpar[5], fpar[6], fpar[7],
                                fpar[8], fpar[9], fpar[10], fpar[11],
                                fpar[12], fpar[13], fpar[14], fpar[15], arr);
  k_tables<<<8, 256, 0, stream>>>(tw, Q, g2);
  k_hs<<<256, 256, 0, stream>>>(arr, Hs);
  k_chat<<<1, 256, 0, stream>>>(tw, chat);
  k_scan<<<NB, 256, 0, stream>>>(x, A1, A2, Asc);
  k_fft_u<<<NB * 9, 256, 0, stream>>>(Asc, tw, U);
  k_main<<<NB * 9, 256, 0, stream>>>(U, Hs, tw, chat, Q, g2, out);
}

// Round 2
// 268.608 us; speedup vs baseline: 1.5997x; 1.5997x over previous
//
#include <hip/hip_runtime.h>
#include <math.h>

#define TN 2048            // T
#define NF 4096            // Bluestein FFT length
#define NB 64              // batch
#define LF 6142LL          // L = 3T-2
#define L2F 12284LL        // 2L
#define PI_D 3.14159265358979323846264338327950288
#define C8 0.70710678118654752440084436210485

typedef double2 cpx;

__device__ __forceinline__ cpx cmk(double a, double b){ cpx r; r.x=a; r.y=b; return r; }
__device__ __forceinline__ cpx cadd(cpx a, cpx b){ return cmk(a.x+b.x, a.y+b.y); }
__device__ __forceinline__ cpx csub(cpx a, cpx b){ return cmk(a.x-b.x, a.y-b.y); }
__device__ __forceinline__ cpx cmul(cpx a, cpx b){ return cmk(a.x*b.x - a.y*b.y, a.x*b.y + a.y*b.x); }
__device__ __forceinline__ cpx cmulc(cpx a, cpx b){ return cmk(a.x*b.x + a.y*b.y, a.y*b.x - a.x*b.y); } // a*conj(b)

// LDS bank-conflict swizzle (cpx granularity, involution)
__device__ __forceinline__ int SW(int i){ return i ^ ((i >> 3) & 7); }

// ---------- 8-point register FFT (DIF, natural in; output position q holds freq R[q])
// R = {0,4,2,6,1,5,3,7}
__device__ __forceinline__ void fft8_bc(cpx* a){
  cpx u, v, d;
  // level B (m=2), tw: [1, -i]
  u=a[0]; v=a[2]; a[0]=cadd(u,v); a[2]=csub(u,v);
  u=a[1]; v=a[3]; a[1]=cadd(u,v); d=csub(u,v); a[3]=cmk(d.y, -d.x);
  u=a[4]; v=a[6]; a[4]=cadd(u,v); a[6]=csub(u,v);
  u=a[5]; v=a[7]; a[5]=cadd(u,v); d=csub(u,v); a[7]=cmk(d.y, -d.x);
  // level C (m=1)
  u=a[0]; v=a[1]; a[0]=cadd(u,v); a[1]=csub(u,v);
  u=a[2]; v=a[3]; a[2]=cadd(u,v); a[3]=csub(u,v);
  u=a[4]; v=a[5]; a[4]=cadd(u,v); a[5]=csub(u,v);
  u=a[6]; v=a[7]; a[6]=cadd(u,v); a[7]=csub(u,v);
}
__device__ __forceinline__ void fft8(cpx* a){
  cpx u, v, d;
  // level A (m=4), tw: [1, (C,-C), -i, (-C,-C)]
  u=a[0]; v=a[4]; a[0]=cadd(u,v); a[4]=csub(u,v);
  u=a[1]; v=a[5]; a[1]=cadd(u,v); d=csub(u,v); a[5]=cmk(C8*(d.x+d.y), C8*(d.y-d.x));
  u=a[2]; v=a[6]; a[2]=cadd(u,v); d=csub(u,v); a[6]=cmk(d.y, -d.x);
  u=a[3]; v=a[7]; a[3]=cadd(u,v); d=csub(u,v); a[7]=cmk(C8*(d.y-d.x), -C8*(d.x+d.y));
  fft8_bc(a);
}
// exact unscaled inverse of fft8 (input in fft8 output positions, output natural, x8)
__device__ __forceinline__ void ifft8(cpx* a){
  cpx u, v, t;
  // level C'
  u=a[0]; v=a[1]; a[0]=cadd(u,v); a[1]=csub(u,v);
  u=a[2]; v=a[3]; a[2]=cadd(u,v); a[3]=csub(u,v);
  u=a[4]; v=a[5]; a[4]=cadd(u,v); a[5]=csub(u,v);
  u=a[6]; v=a[7]; a[6]=cadd(u,v); a[7]=csub(u,v);
  // level B' (conj tw: [1, +i])
  u=a[0]; v=a[2]; a[0]=cadd(u,v); a[2]=csub(u,v);
  u=a[1]; t=a[3]; v=cmk(-t.y, t.x); a[1]=cadd(u,v); a[3]=csub(u,v);
  u=a[4]; v=a[6]; a[4]=cadd(u,v); a[6]=csub(u,v);
  u=a[5]; t=a[7]; v=cmk(-t.y, t.x); a[5]=cadd(u,v); a[7]=csub(u,v);
  // level A' (conj tw: [1, (C,C), +i, (-C,C)])
  u=a[0]; v=a[4]; a[0]=cadd(u,v); a[4]=csub(u,v);
  u=a[1]; t=a[5]; v=cmk(C8*(t.x-t.y), C8*(t.x+t.y)); a[1]=cadd(u,v); a[5]=csub(u,v);
  u=a[2]; t=a[6]; v=cmk(-t.y, t.x); a[2]=cadd(u,v); a[6]=csub(u,v);
  u=a[3]; t=a[7]; v=cmk(-C8*(t.x+t.y), C8*(t.x-t.y)); a[3]=cadd(u,v); a[7]=csub(u,v);
}
// 4-point DIF; output position q holds freq R4[q], R4 = {0,2,1,3}
__device__ __forceinline__ void fft4(cpx* a){
  cpx u, v, d;
  u=a[0]; v=a[2]; a[0]=cadd(u,v); a[2]=csub(u,v);
  u=a[1]; v=a[3]; a[1]=cadd(u,v); d=csub(u,v); a[3]=cmk(d.y, -d.x);
  u=a[0]; v=a[1]; a[0]=cadd(u,v); a[1]=csub(u,v);
  u=a[2]; v=a[3]; a[2]=cadd(u,v); a[3]=csub(u,v);
}

// ---------- generic radix-8 DIF / inverse-DIT stages (in-place in LDS through SW).
// tw[k] = e^{-2pi i k/4096}, k<4096. block size n = 8*2^LM; twiddle W_n^{pos*k} = tw[(pos*k)<<(9-LM)].
template<int LM, int NBF>
__device__ __forceinline__ void r8_stage_fwd(cpx* buf, const cpx* tw){
  const int R[8] = {0,4,2,6,1,5,3,7};
  for (int b = threadIdx.x; b < NBF; b += 256){
    int pos = b & ((1 << LM) - 1);
    int base = ((b >> LM) << (LM + 3)) | pos;
    cpx a[8];
    #pragma unroll
    for (int j = 0; j < 8; j++) a[j] = buf[SW(base + (j << LM))];
    fft8(a);
    #pragma unroll
    for (int q = 0; q < 8; q++){
      int k = R[q];
      cpx v = a[q];
      if (k) v = cmul(v, tw[(pos * k) << (9 - LM)]);
      buf[SW(base + (k << LM))] = v;
    }
  }
}
template<int LM, int NBF>
__device__ __forceinline__ void r8_stage_inv(cpx* buf, const cpx* tw){
  const int R[8] = {0,4,2,6,1,5,3,7};
  for (int b = threadIdx.x; b < NBF; b += 256){
    int pos = b & ((1 << LM) - 1);
    int base = ((b >> LM) << (LM + 3)) | pos;
    cpx a[8];
    #pragma unroll
    for (int q = 0; q < 8; q++){
      int k = R[q];
      cpx v = buf[SW(base + (k << LM))];
      a[q] = k ? cmulc(v, tw[(pos * k) << (9 - LM)]) : v;
    }
    ifft8(a);
    #pragma unroll
    for (int j = 0; j < 8; j++) buf[SW(base + (j << LM))] = a[j];
  }
}

// ---------- K1: filters + tables
__global__ __launch_bounds__(256) void k_prep(
    const float* fw1, const float* fb1, const float* fw2, const float* fb2,
    const float* gw1, const float* gb1, const float* gw2, const float* gb2,
    const float* pw1, const float* pb1, const float* pw2, const float* pb2,
    const float* qw1, const float* qb1, const float* qw2, const float* qb2,
    double* arr, cpx* tw, cpx* Q, cpx* g2)
{
  int gid = blockIdx.x * 256 + threadIdx.x;   // < 8192
  if (gid < 4096){
    double s, c;
    sincos(-2.0 * PI_D * (double)gid / 4096.0, &s, &c);
    tw[gid] = cmk(c, s);
  }
  if (gid < 2048){
    long long i = gid;
    double s, c;
    long long a = ((2LL * TN - 2) * i) % LF;
    long long b = (i * i) % L2F;
    long long comb = (2 * a + b) % L2F;
    sincos(PI_D * (double)comb / (double)LF, &s, &c);
    Q[gid] = cmk(c, s);
    long long a2 = ((2LL * TN - 2 + i) * (TN - 1)) % LF;
    long long comb2 = (2 * a2 + b) % L2F;
    double phi = PI_D * (double)comb2 / (double)LF;
    double scale = 1.0 / ((double)LF * (double)LF) / (4096.0 * 4096.0);
    sincos(2.0 * phi, &s, &c);
    g2[gid] = cmk(c * scale, s * scale);
  }
  // filter arrays: fid 0=f,1=g,2=fp,3=gp (f,fp time-reversed)
  int fid = gid >> 11;
  int m = gid & (TN - 1);
  const float *W1, *B1, *W2, *B2;
  if (fid == 0){ W1=fw1; B1=fb1; W2=fw2; B2=fb2; }
  else if (fid == 1){ W1=gw1; B1=gb1; W2=gw2; B2=gb2; }
  else if (fid == 2){ W1=pw1; B1=pb1; W2=pw2; B2=pb2; }
  else { W1=qw1; B1=qb1; W2=qw2; B2=qb2; }
  int s = (fid == 0 || fid == 2) ? (TN - 1 - m) : m;
  double sv = (double)s;
  double z = (double)B2[0];
  #pragma unroll
  for (int h = 0; h < 5; h++)
    z += (double)W2[h] * tanh(sv * (double)W1[h] + (double)B1[h]);
  arr[fid * TN + m] = z * exp(-5.0 * sv);
}

// ---------- SO(3) helpers
__device__ __forceinline__ void mat_mul3(double* D, const double* A, const double* B){
  double r[9];
  #pragma unroll
  for (int i = 0; i < 3; i++)
    #pragma unroll
    for (int j = 0; j < 3; j++)
      r[i*3+j] = A[i*3]*B[j] + A[i*3+1]*B[3+j] + A[i*3+2]*B[6+j];
  #pragma unroll
  for (int k = 0; k < 9; k++) D[k] = r[k];
}
__device__ __forceinline__ void rod3(double* M, const double* a1, const double* a2,
                                     double z1, double z2){
  double G[9];
  #pragma unroll
  for (int k = 0; k < 9; k++) G[k] = a1[k]*z1 + a2[k]*z2;
  double wx = G[7], wy = G[2], wz = G[3];
  double th2 = wx*wx + wy*wy + wz*wz;
  double sa, cb;
  if (th2 < 1e-12){ sa = 1.0 - th2/6.0; cb = 0.5 - th2/24.0; }
  else { double th = sqrt(th2); sa = sin(th)/th; cb = (1.0 - cos(th))/th2; }
  double w[3] = {wx, wy, wz};
  #pragma unroll
  for (int i = 0; i < 3; i++)
    #pragma unroll
    for (int j = 0; j < 3; j++){
      double v = sa * G[i*3+j] + cb * (w[i]*w[j]);
      if (i == j) v += 1.0 - cb * th2;
      M[i*3+j] = v;
    }
}

// ---------- K2 merged: blocks 0-255 = H spectra (xQ folded), 256-319 = SO(3) scan, 320 = chat
__global__ __launch_bounds__(256) void k_front(
    const float* x, const float* A1f, const float* A2f,
    const double* arr, const cpx* Q, const cpx* tw,
    cpx* HsQ, double* Asc, cpx* chat)
{
  __shared__ double smem[8192];   // 64 KB union
  int tid = threadIdx.x;
  int bid = blockIdx.x;
  if (bid < 256){
    // ---- Hs * Q
    cpx* part = (cpx*)smem;
    int f = bid >> 6;
    int jbase = (bid & 63) * 32;
    int chunk = tid & 7;
    int jl = tid >> 3;
    long long j = jbase + jl;
    long long jj = j + TN - 1;
    double s, c;
    sincos(-2.0 * PI_D * (double)jj / (double)LF, &s, &c);
    cpx W = cmk(c, s);
    long long m0 = (long long)chunk * 256;
    long long p0 = ((m0 + TN - 1) * jj) % LF;
    sincos(-2.0 * PI_D * (double)p0 / (double)LF, &s, &c);
    cpx ph = cmk(c, s);
    const double* a = arr + f * TN;
    cpx acc = cmk(0.0, 0.0);
    for (int m = (int)m0; m < (int)m0 + 256; m++){
      double av = a[m];
      acc.x += av * ph.x;
      acc.y += av * ph.y;
      ph = cmul(ph, W);
    }
    part[tid] = acc;
    __syncthreads();
    if (chunk == 0){
      cpx tot = cmk(0.0, 0.0);
      for (int q = 0; q < 8; q++) tot = cadd(tot, part[(jl << 3) + q]);
      HsQ[f * TN + (int)j] = cmul(tot, Q[j]);
    }
  } else if (bid < 320){
    // ---- rotation prefix scan, output layout [b][c][t]
    int b = bid - 256;
    double (*S)[9] = (double(*)[9])smem;
    int k = tid;
    double a1[9], a2[9];
    #pragma unroll
    for (int i = 0; i < 3; i++)
      #pragma unroll
      for (int j = 0; j < 3; j++){
        a1[i*3+j] = (double)A1f[i*3+j] - (double)A1f[j*3+i];
        a2[i*3+j] = (double)A2f[i*3+j] - (double)A2f[j*3+i];
      }
    const float* xb = x + (size_t)b * TN * 2;
    double C[9] = {1,0,0, 0,1,0, 0,0,1};
    for (int i = 0; i < 8; i++){
      int t = k * 8 + i;
      if (t >= 1){
        double M[9];
        rod3(M, a1, a2, (double)xb[2*t], (double)xb[2*t+1]);
        mat_mul3(C, C, M);
      }
    }
    #pragma unroll
    for (int q = 0; q < 9; q++) S[k][q] = C[q];
    __syncthreads();
    for (int ofs = 1; ofs < 256; ofs <<= 1){
      double Lm[9], Rm[9];
      bool act = (k >= ofs);
      if (act){
        #pragma unroll
        for (int q = 0; q < 9; q++){ Lm[q] = S[k-ofs][q]; Rm[q] = S[k][q]; }
      }
      __syncthreads();
      if (act){
        double P[9];
        mat_mul3(P, Lm, Rm);
        #pragma unroll
        for (int q = 0; q < 9; q++) S[k][q] = P[q];
      }
      __syncthreads();
    }
    double P[9];
    if (k == 0){
      P[0]=1; P[1]=0; P[2]=0; P[3]=0; P[4]=1; P[5]=0; P[6]=0; P[7]=0; P[8]=1;
    } else {
      #pragma unroll
      for (int q = 0; q < 9; q++) P[q] = S[k-1][q];
    }
    for (int i = 0; i < 8; i++){
      int t = k * 8 + i;
      if (t >= 1){
        double M[9];
        rod3(M, a1, a2, (double)xb[2*t], (double)xb[2*t+1]);
        mat_mul3(P, P, M);
      }
      #pragma unroll
      for (int q = 0; q < 9; q++)
        Asc[(((size_t)b * 9 + q) << 11) + t] = P[q];
    }
  } else {
    // ---- chat = DIF4096(chirp), stored in DIF storage order
    cpx* buf = (cpx*)smem;
    for (int m = tid; m < NF; m += 256){
      long long mm = (m <= 2048) ? m : (NF - m);
      long long q = (mm * mm) % L2F;
      double s, c;
      sincos(-PI_D * (double)q / (double)LF, &s, &c);
      buf[SW(m)] = cmk(c, s);
    }
    __syncthreads();
    r8_stage_fwd<9,512>(buf, tw); __syncthreads();
    r8_stage_fwd<6,512>(buf, tw); __syncthreads();
    r8_stage_fwd<3,512>(buf, tw); __syncthreads();
    r8_stage_fwd<0,512>(buf, tw); __syncthreads();
    for (int i = tid; i < NF; i += 256) chat[i] = buf[SW(i)];
  }
}

// ---------- K3: 2048-pt FFT per (b,c) channel -> U natural order. radices 8,8,8,4
__global__ __launch_bounds__(256, 2) void k_fft_u(const double* Asc, const cpx* tw, cpx* U){
  __shared__ cpx buf[TN];
  int tid = threadIdx.x;
  const double* src = Asc + ((size_t)blockIdx.x << 11);
  for (int t = tid; t < TN; t += 256) buf[SW(t)] = cmk(src[t], 0.0);
  __syncthreads();
  r8_stage_fwd<8,256>(buf, tw); __syncthreads();
  r8_stage_fwd<5,256>(buf, tw); __syncthreads();
  r8_stage_fwd<2,256>(buf, tw); __syncthreads();
  // final radix-4 (m=1, pos=0): gather all reads first, then scatter to natural-f LDS
  const int R4[4] = {0,2,1,3};
  cpx rr[2][4];
  #pragma unroll
  for (int it = 0; it < 2; it++){
    int b = tid + (it << 8);
    cpx a[4];
    #pragma unroll
    for (int j = 0; j < 4; j++) a[j] = buf[SW((b << 2) + j)];
    fft4(a);
    #pragma unroll
    for (int q = 0; q < 4; q++) rr[it][q] = a[q];
  }
  __syncthreads();
  #pragma unroll
  for (int it = 0; it < 2; it++){
    int b = tid + (it << 8);
    int fb = (b >> 6) + (((b >> 3) & 7) << 3) + ((b & 7) << 6);
    #pragma unroll
    for (int q = 0; q < 4; q++)
      buf[SW(fb + (R4[q] << 9))] = rr[it][q];
  }
  __syncthreads();
  cpx* dst = U + ((size_t)blockIdx.x << 11);
  for (int i = tid; i < TN; i += 256) dst[i] = buf[SW(i)];
}

// ---------- K4: main CZT. Per (b,c): 4x (fused stage1 -> r8 x2 -> fused S4*chat*I1 ->
// r8inv x2 -> fused I4 into registers), combine with g2.
__global__ __launch_bounds__(256, 2) void k_main(const cpx* U, const cpx* HsQ, const cpx* tw,
                                                 const cpx* chat, const cpx* g2, float* out){
  int bc = blockIdx.x;
  int b = bc / 9, c = bc % 9;
  int ct = (c % 3) * 3 + (c / 3);        // inv(A) = A^T for SO(3)
  const cpx* Uc  = U + ((size_t)b * 9 + c)  * TN;
  const cpx* Uct = U + ((size_t)b * 9 + ct) * TN;
  __shared__ cpx buf[NF];
  int tid = threadIdx.x;
  const int R[8] = {0,4,2,6,1,5,3,7};
  cpx pst[2][4], acc[2][4];
  #pragma unroll
  for (int it = 0; it < 2; it++)
    #pragma unroll
    for (int j = 0; j < 4; j++) acc[it][j] = cmk(0.0, 0.0);

  for (int p = 0; p < 4; p++){           // AA, AB, BA, BB
    const cpx* Us = (p & 1) ? Uc : Uct;
    const cpx* H = HsQ + p * TN;
    __syncthreads();
    // S1 (n=4096): staging fused, upper half zero
    #pragma unroll
    for (int it = 0; it < 2; it++){
      int pos = tid + (it << 8);
      cpx a[8];
      #pragma unroll
      for (int j = 0; j < 4; j++){
        int idx = pos + (j << 9);
        a[j] = cmul(Us[idx], H[idx]);
      }
      // level A with a[4..7]=0
      a[4] = a[0];
      a[5] = cmk(C8*(a[1].x + a[1].y), C8*(a[1].y - a[1].x));
      a[6] = cmk(a[2].y, -a[2].x);
      a[7] = cmk(C8*(a[3].y - a[3].x), -C8*(a[3].x + a[3].y));
      fft8_bc(a);
      #pragma unroll
      for (int q = 0; q < 8; q++){
        int k = R[q];
        cpx v = a[q];
        if (k) v = cmul(v, tw[pos * k]);
        buf[SW(pos + (k << 9))] = v;
      }
    }
    __syncthreads();
    r8_stage_fwd<6,512>(buf, tw);
    __syncthreads();
    r8_stage_fwd<3,512>(buf, tw);
    __syncthreads();
    // S4 (n=8) + chat + I1 (n=8) fused in registers (pos=0 -> unit twiddles)
    #pragma unroll
    for (int it = 0; it < 2; it++){
      int base = (tid + (it << 8)) << 3;
      cpx a[8];
      #pragma unroll
      for (int j = 0; j < 8; j++) a[j] = buf[SW(base + j)];
      fft8(a);
      #pragma unroll
      for (int q = 0; q < 8; q++) a[q] = cmul(a[q], chat[base + R[q]]);
      ifft8(a);
      #pragma unroll
      for (int j = 0; j < 8; j++) buf[SW(base + j)] = a[j];
    }
    __syncthreads();
    r8_stage_inv<3,512>(buf, tw);
    __syncthreads();
    r8_stage_inv<6,512>(buf, tw);
    __syncthreads();
    // I4 (n=4096): only r<2048 outputs, kept in registers
    #pragma unroll
    for (int it = 0; it < 2; it++){
      int pos = tid + (it << 8);
      cpx a[8];
      #pragma unroll
      for (int q = 0; q < 8; q++){
        int k = R[q];
        cpx v = buf[SW(pos + (k << 9))];
        a[q] = k ? cmulc(v, tw[pos * k]) : v;
      }
      ifft8(a);
      #pragma unroll
      for (int j = 0; j < 4; j++){
        if ((p & 1) == 0) pst[it][j] = a[j];
        else acc[it][j] = cadd(acc[it][j], cmul(pst[it][j], a[j]));
      }
    }
  }
  #pragma unroll
  for (int it = 0; it < 2; it++)
    #pragma unroll
    for (int j = 0; j < 4; j++){
      int r = tid + (it << 8) + (j << 9);
      cpx g = g2[r];
      out[((size_t)b * TN + r) * 9 + c] = (float)(acc[it][j].x * g.x - acc[it][j].y * g.y);
    }
}

extern "C" void kernel_launch(void* const* d_in, const int* in_sizes, int n_in,
                              void* d_out, int out_size, void* d_ws, size_t ws_size,
                              hipStream_t stream){
  const float* x  = (const float*)d_in[0];
  const float* A1 = (const float*)d_in[1];
  const float* A2 = (const float*)d_in[2];
  const float* fpar[16];
  for (int i = 0; i < 16; i++) fpar[i] = (const float*)d_in[3 + i];
  float* out = (float*)d_out;

  // workspace carve (units: doubles), total ~28.7 MB
  double* ws = (double*)d_ws;
  size_t o = 0;
  double* arr  = ws + o;         o += 4 * TN;                   // 8192
  cpx* HsQ     = (cpx*)(ws + o); o += 2 * 4 * TN;               // 4x2048 cpx
  cpx* tw      = (cpx*)(ws + o); o += 2 * NF;                   // 4096 cpx
  cpx* chat    = (cpx*)(ws + o); o += 2 * NF;
  cpx* Q       = (cpx*)(ws + o); o += 2 * TN;
  cpx* g2      = (cpx*)(ws + o); o += 2 * TN;
  double* Asc  = ws + o;         o += (size_t)NB * TN * 9;      // 9.4 MB
  cpx* U       = (cpx*)(ws + o); o += 2 * (size_t)NB * 9 * TN;  // 18.9 MB

  k_prep<<<32, 256, 0, stream>>>(fpar[0], fpar[1], fpar[2], fpar[3],
                                 fpar[4], fpar[5], fpar[6], fpar[7],
                                 fpar[8], fpar[9], fpar[10], fpar[11],
                                 fpar[12], fpar[13], fpar[14], fpar[15],
                                 arr, tw, Q, g2);
  k_front<<<321, 256, 0, stream>>>(x, A1, A2, arr, Q, tw, HsQ, Asc, chat);
  k_fft_u<<<NB * 9, 256, 0, stream>>>(Asc, tw, U);
  k_main<<<NB * 9, 256, 0, stream>>>(U, HsQ, tw, chat, g2, out);
}